// Round 9
// baseline (289.636 us; speedup 1.0000x reference)
//
#include <hip/hip_runtime.h>

typedef _Float16 f16x8 __attribute__((ext_vector_type(8)));
typedef float    f32x4 __attribute__((ext_vector_type(4)));
typedef float    f32x2 __attribute__((ext_vector_type(2)));

#define NSTEP 512
#define CHUNK 8
#define NCHUNK (NSTEP / CHUNK)
#define LOG2E     1.4426950408889634f
#define TWOLOG2E  2.8853900817779268f

__device__ __forceinline__ float exp2_(float v) { return __builtin_amdgcn_exp2f(v); }

// Packed-pair exp2-domain LSTM activation: the A/B cells' independent
// element-wise chains computed as float2 so the backend can emit
// v_pk_fma/add/mul_f32 for the arithmetic (trans ops remain scalar).
// Gates arrive PRE-SCALED from the MFMA: gi,gf,go = -log2e*preact,
// gg = +2log2e*preact. Same fused ops / same order as the scalar version.
__device__ __forceinline__ f32x2 exp2v_(f32x2 v) {
    f32x2 r; r[0] = exp2_(v[0]); r[1] = exp2_(v[1]); return r;
}
__device__ __forceinline__ f32x2 rcpv_(f32x2 v) {
    f32x2 r; r[0] = __builtin_amdgcn_rcpf(v[0]); r[1] = __builtin_amdgcn_rcpf(v[1]); return r;
}
__device__ __forceinline__ f32x2 lstm_act2_(f32x2 gi, f32x2 gf, f32x2 gg, f32x2 go, f32x2& c) {
    const f32x2 one = {1.0f, 1.0f};
    f32x2 eg = exp2v_(gg);
    f32x2 ei = exp2v_(gi);
    f32x2 ef = exp2v_(gf);
    f32x2 eo = exp2v_(go);
    f32x2 X  = (eg + one) * (one + ei);
    f32x2 Y  = one + ef;
    f32x2 r  = rcpv_(X * Y);
    c = (r * X) * c + (eg - one) * (r * Y);
    f32x2 ec;
    ec[0] = exp2_(fminf(c[0] * TWOLOG2E, 30.0f));
    ec[1] = exp2_(fminf(c[1] * TWOLOG2E, 30.0f));
    f32x2 r2 = rcpv_((ec + one) * (one + eo));
    return (ec - one) * r2;
}
__device__ __forceinline__ float sig_(float v) {
    return __builtin_amdgcn_rcpf(1.0f + exp2_(-v * LOG2E));
}
__device__ __forceinline__ float tanh_(float v) {
    return 1.0f - 2.0f * __builtin_amdgcn_rcpf(exp2_(v * TWOLOG2E) + 1.0f);
}

// lgkmcnt-only barrier: does NOT drain vmcnt, so global x-prefetch loads float
// across the whole chunk. asm "memory" fences pin LDS ops on both sides.
__device__ __forceinline__ void bar_() {
    asm volatile("s_waitcnt lgkmcnt(0)" ::: "memory");
    __builtin_amdgcn_s_barrier();
    asm volatile("" ::: "memory");
}

// R24 = R23 (8 waves x 2 tiles, 1 bar/step, chunk-burst ax, packed act,
// spread emb writes, vmcnt-floating prefetch) + independent MFMA pair:
// a0 = mfma(whh0,f0,ax), a1 = mfma(whh1,f1,0) issue in parallel (no C-chain
// between them) and are combined with packed f32x2 adds -- removes one
// MFMA-latency hop from the serial recurrence chain. Summation order is the
// round-0-verified (a0+a1) form. R22 tested this bundled with a harmful
// per-step ax filler; this isolates it.
__global__ __launch_bounds__(512, 2) void lstm_mfma16_kernel(
    const float* __restrict__ x,     const float* __restrict__ Wemb,
    const float* __restrict__ Wih1,  const float* __restrict__ Whh1,
    const float* __restrict__ b1,    const float* __restrict__ Wih2,
    const float* __restrict__ b2,    const float* __restrict__ Wout,
    const float* __restrict__ bout,  float* __restrict__ out)
{
    __shared__ __align__(16) _Float16 P[2][2][4][16][8];       // 4096 B  h-panel dbuf
    __shared__ __align__(16) _Float16 Pe[2][CHUNK][4][16][8];  // 16384 B emb panel dbuf
    __shared__ __align__(16) float h2tmp[16 * 64];             // 4096 B
    __shared__ __align__(16) float h2s[256 * 16];              // 16384 B
    __shared__ float part[32 * 16 * 2];                        // 4096 B

    const int t   = threadIdx.x;
    const int l   = t & 63;
    const int w   = t >> 6;      // wave 0..7; owns tiles 2w, 2w+1
    const int m   = l & 15;      // A-row / B col (batch) / D col
    const int q   = l >> 4;      // quad
    const int b0  = blockIdx.x * 16;

    // ---- weight fragments for both tiles (exp2-domain scaled) --------------
    f16x8 whh[2][2], whE[2];
    f32x4 bias4[2];
    #pragma unroll
    for (int tt = 0; tt < 2; ++tt) {
        const int tau = 2 * w + tt;
        const int g = m & 3;
        const float sc = (g == 2) ? TWOLOG2E : -LOG2E;
        const int n = g * 64 + 4 * tau + (m >> 2);
        #pragma unroll
        for (int c = 0; c < 2; ++c)
            #pragma unroll
            for (int jj = 0; jj < 8; ++jj)
                whh[tt][c][jj] = (_Float16)(Whh1[n * 64 + c * 32 + (q << 3) + jj] * sc);
        #pragma unroll
        for (int jj = 0; jj < 8; ++jj) {
            int k = (q << 3) + jj;
            whE[tt][jj] = (_Float16)((k < 20) ? Wih1[n * 20 + k] * sc : 0.0f);
        }
        #pragma unroll
        for (int r = 0; r < 4; ++r) {
            float scr = (r == 2) ? TWOLOG2E : -LOG2E;
            bias4[tt][r] = b1[r * 64 + 4 * tau + q] * scr;
        }
    }
    const f32x4 z4 = {0.f, 0.f, 0.f, 0.f};

    // lane's act cells: units 8w+q (tile A), 8w+4+q (tile B), batch m
    const int myuA = 8 * w + q;
    const int myuB = 8 * w + 4 + q;
    _Float16* hwA = &P[0][myuA >> 5][(myuA >> 3) & 3][m][myuA & 7];
    _Float16* hwB = &P[0][myuB >> 5][(myuB >> 3) & 3][m][myuB & 7];
    const _Float16* rb = &P[0][0][q][m][0];   // B-fragment base (lane-linear)
    // parity stride = one P buffer = 1024 f16; Pe buffer stride = 4096 f16

    // ---- emb writer slots: v = t + 512k, k=0..4 (2560 = 5*512, all valid) --
    // pair = v/20 -> (batch = pair&15, s = pair>>4), dim d = v%20
    const float* xp[5]; _Float16* pe[5];
    float we0[5], we1[5];
    float2 xv[5];
    #pragma unroll
    for (int k = 0; k < 5; ++k) {
        int v  = t + 512 * k;
        int d  = v % 20, pr = v / 20;
        int bb = pr & 15, s = pr >> 4;
        we0[k] = Wemb[2 * d];
        we1[k] = Wemb[2 * d + 1];
        pe[k]  = &Pe[0][s][d >> 3][bb][d & 7];
        xp[k]  = x + (size_t)(b0 + bb) * (2 * NSTEP) + 2 * s;
        xv[k]  = *(const float2*)xp[k];                    // chunk-0 data
    }

    // ---- zero P[0] (h(-1)=0) and all of Pe (pads d=20..31 stay 0 forever) --
    ((_Float16*)P)[t]       = (_Float16)0.0f;
    ((_Float16*)P)[t + 512] = (_Float16)0.0f;
    {
        _Float16* pz = (_Float16*)Pe;
        #pragma unroll
        for (int k = 0; k < 16; ++k) pz[t + 512 * k] = (_Float16)0.0f;
    }
    __syncthreads();
    // fill Pe[0] with chunk 0's panel, then prefetch chunk 1's x
    #pragma unroll
    for (int k = 0; k < 5; ++k)
        pe[k][0] = (_Float16)fmaxf(fmaf(xv[k].x, we0[k], xv[k].y * we1[k]), 0.0f);
    #pragma unroll
    for (int k = 0; k < 5; ++k) { xp[k] += 2 * CHUNK; xv[k] = *(const float2*)xp[k]; }
    __syncthreads();

    // ---- main recurrence: 64 chunks x 8 steps ------------------------------
    f32x2 cst = {0.0f, 0.0f};
    for (int ch = 0; ch < NCHUNK; ++ch) {
        const int pb = ch & 1;                           // Pe read buffer
        const _Float16* peR = (const _Float16*)Pe + pb * 4096;

        // phase B: ax[tile][j] = Wih*e(t) + b, in registers (lane == consumer)
        f32x4 axA[CHUNK], axB[CHUNK];
        #pragma unroll
        for (int j = 0; j < CHUNK; ++j) {
            f16x8 fe = *(const f16x8*)(peR + j * 512 + q * 128 + m * 8);
            axA[j] = __builtin_amdgcn_mfma_f32_16x16x32_f16(whE[0], fe, bias4[0], 0, 0, 0);
            axB[j] = __builtin_amdgcn_mfma_f32_16x16x32_f16(whE[1], fe, bias4[1], 0, 0, 0);
        }

        // phase C: 8 recurrence steps, parity static per unrolled slot
        #pragma unroll
        for (int j = 0; j < CHUNK; ++j) {
            const int pr = j & 1;
            f16x8 f0 = *(const f16x8*)(rb + pr * 1024);
            f16x8 f1 = *(const f16x8*)(rb + pr * 1024 + 512);
            // independent MFMA pair per tile (no C-chain), packed combines
            f32x4 aA0 = __builtin_amdgcn_mfma_f32_16x16x32_f16(whh[0][0], f0, axA[j], 0, 0, 0);
            f32x4 aB0 = __builtin_amdgcn_mfma_f32_16x16x32_f16(whh[1][0], f0, axB[j], 0, 0, 0);
            f32x4 aA1 = __builtin_amdgcn_mfma_f32_16x16x32_f16(whh[0][1], f1, z4, 0, 0, 0);
            f32x4 aB1 = __builtin_amdgcn_mfma_f32_16x16x32_f16(whh[1][1], f1, z4, 0, 0, 0);
            f32x2 gi = {aA0[0] + aA1[0], aB0[0] + aB1[0]};
            f32x2 gf = {aA0[1] + aA1[1], aB0[1] + aB1[1]};
            f32x2 gg = {aA0[2] + aA1[2], aB0[2] + aB1[2]};
            f32x2 go = {aA0[3] + aA1[3], aB0[3] + aB1[3]};
            f32x2 hv = lstm_act2_(gi, gf, gg, go, cst);
            hwA[(pr ^ 1) * 1024] = (_Float16)hv[0];
            hwB[(pr ^ 1) * 1024] = (_Float16)hv[1];
            // emb writes for chunk ch+1 spread one per step (j=1..5);
            // x prefetch for chunk ch+2 at j=6. Pe[pb^1]'s first reader is
            // next chunk's phase B (after this chunk's last barrier);
            // last chunk writes stale data to a dead buffer.
            if (j >= 1 && j <= 5) {
                const int k = j - 1;
                pe[k][(pb ^ 1) * 4096] =
                    (_Float16)fmaxf(fmaf(xv[k].x, we0[k], xv[k].y * we1[k]), 0.0f);
            }
            if (j == 6 && ch + 2 < NCHUNK) {
                #pragma unroll
                for (int k = 0; k < 5; ++k) { xp[k] += 2 * CHUNK; xv[k] = *(const float2*)xp[k]; }
            }
            bar_();
        }
    }
    // final h(511) in P[0]

    // ---- epilogue: h64 to fp32 (1024 values, two per thread) ---------------
    #pragma unroll
    for (int r = 0; r < 2; ++r) {
        int tt = t + 512 * r;
        int b = tt >> 6, k = tt & 63;
        h2tmp[tt] = (float)P[0][k >> 5][(k >> 3) & 3][b][k & 7];
    }
    __syncthreads();

    // ---- LSTM2 (single step, h=c=0 -> f-gate irrelevant) -------------------
    {
        const int u = t & 255;
        const int bh0 = (t >> 8) * 8;               // 2 groups x 8 batches
        float acci[8], accg[8], acco[8];
        float bi2 = b2[u], bg2 = b2[512 + u], bo2 = b2[768 + u];
        #pragma unroll
        for (int b = 0; b < 8; ++b) { acci[b] = bi2; accg[b] = bg2; acco[b] = bo2; }
        for (int k4 = 0; k4 < 64; k4 += 4) {
            float4 wi = *(const float4*)&Wih2[(size_t)u * 64 + k4];
            float4 wg = *(const float4*)&Wih2[(size_t)(512 + u) * 64 + k4];
            float4 wo = *(const float4*)&Wih2[(size_t)(768 + u) * 64 + k4];
            #pragma unroll
            for (int b = 0; b < 8; ++b) {
                float4 hb = *(const float4*)&h2tmp[(bh0 + b) * 64 + k4];
                acci[b] += wi.x * hb.x + wi.y * hb.y + wi.z * hb.z + wi.w * hb.w;
                accg[b] += wg.x * hb.x + wg.y * hb.y + wg.z * hb.z + wg.w * hb.w;
                acco[b] += wo.x * hb.x + wo.y * hb.y + wo.z * hb.z + wo.w * hb.w;
            }
        }
        #pragma unroll
        for (int b = 0; b < 8; ++b) {
            float c2 = sig_(acci[b]) * tanh_(accg[b]);
            h2s[u * 16 + bh0 + b] = sig_(acco[b]) * tanh_(c2);
        }
    }
    __syncthreads();

    // ---- output projection --------------------------------------------------
    {
        int b = t & 15, grp = t >> 4;            // 32 groups x 8 units
        float p0 = 0.f, p1 = 0.f;
        #pragma unroll
        for (int uu = grp * 8; uu < grp * 8 + 8; ++uu) {
            float hvv = h2s[uu * 16 + b];
            p0 += hvv * Wout[uu];
            p1 += hvv * Wout[256 + uu];
        }
        part[(grp * 16 + b) * 2 + 0] = p0;
        part[(grp * 16 + b) * 2 + 1] = p1;
    }
    __syncthreads();
    if (t < 32) {
        int b = t >> 1, o = t & 1;
        float s0 = bout[o];
        for (int grp = 0; grp < 32; ++grp) s0 += part[(grp * 16 + b) * 2 + o];
        out[(size_t)(b0 + b) * 2 + o] = s0;
    }
}

extern "C" void kernel_launch(void* const* d_in, const int* in_sizes, int n_in,
                              void* d_out, int out_size, void* d_ws, size_t ws_size,
                              hipStream_t stream) {
    const float* x    = (const float*)d_in[0];
    const float* Wemb = (const float*)d_in[1];
    const float* Wih1 = (const float*)d_in[2];
    const float* Whh1 = (const float*)d_in[3];
    const float* b1   = (const float*)d_in[4];
    const float* Wih2 = (const float*)d_in[5];
    // d_in[6] = Whh2: unused (h=c=0 at LSTM2's single step)
    const float* b2   = (const float*)d_in[7];
    const float* Wout = (const float*)d_in[8];
    const float* bout = (const float*)d_in[9];
    float* out = (float*)d_out;

    lstm_mfma16_kernel<<<256, 512, 0, stream>>>(
        x, Wemb, Wih1, Whh1, b1, Wih2, b2, Wout, bout, out);
}

// Round 10
// 281.577 us; speedup vs baseline: 1.0286x; 1.0286x over previous
//
#include <hip/hip_runtime.h>

typedef _Float16 f16x8 __attribute__((ext_vector_type(8)));
typedef float    f32x4 __attribute__((ext_vector_type(4)));
typedef float    f32x2 __attribute__((ext_vector_type(2)));

#define NSTEP 512
#define CHUNK 8
#define NCHUNK (NSTEP / CHUNK)
#define LOG2E     1.4426950408889634f
#define TWOLOG2E  2.8853900817779268f

__device__ __forceinline__ float exp2_(float v) { return __builtin_amdgcn_exp2f(v); }

// Packed-pair exp2-domain LSTM activation: the A/B cells' independent
// element-wise chains computed as float2 so the backend can emit
// v_pk_fma/add/mul_f32 for the arithmetic (trans ops remain scalar).
// Gates arrive PRE-SCALED from the MFMA: gi,gf,go = -log2e*preact,
// gg = +2log2e*preact. Same fused ops / same order as the scalar version.
__device__ __forceinline__ f32x2 exp2v_(f32x2 v) {
    f32x2 r; r[0] = exp2_(v[0]); r[1] = exp2_(v[1]); return r;
}
__device__ __forceinline__ f32x2 rcpv_(f32x2 v) {
    f32x2 r; r[0] = __builtin_amdgcn_rcpf(v[0]); r[1] = __builtin_amdgcn_rcpf(v[1]); return r;
}
__device__ __forceinline__ f32x2 lstm_act2_(f32x2 gi, f32x2 gf, f32x2 gg, f32x2 go, f32x2& c) {
    const f32x2 one = {1.0f, 1.0f};
    f32x2 eg = exp2v_(gg);
    f32x2 ei = exp2v_(gi);
    f32x2 ef = exp2v_(gf);
    f32x2 eo = exp2v_(go);
    f32x2 X  = (eg + one) * (one + ei);
    f32x2 Y  = one + ef;
    f32x2 r  = rcpv_(X * Y);
    c = (r * X) * c + (eg - one) * (r * Y);
    f32x2 ec;
    ec[0] = exp2_(fminf(c[0] * TWOLOG2E, 30.0f));
    ec[1] = exp2_(fminf(c[1] * TWOLOG2E, 30.0f));
    f32x2 r2 = rcpv_((ec + one) * (one + eo));
    return (ec - one) * r2;
}
__device__ __forceinline__ float sig_(float v) {
    return __builtin_amdgcn_rcpf(1.0f + exp2_(-v * LOG2E));
}
__device__ __forceinline__ float tanh_(float v) {
    return 1.0f - 2.0f * __builtin_amdgcn_rcpf(exp2_(v * TWOLOG2E) + 1.0f);
}

// lgkmcnt-only barrier: does NOT drain vmcnt, so global x-prefetch loads float
// across the whole chunk. asm "memory" fences pin LDS ops on both sides.
__device__ __forceinline__ void bar_() {
    asm volatile("s_waitcnt lgkmcnt(0)" ::: "memory");
    __builtin_amdgcn_s_barrier();
    asm volatile("" ::: "memory");
}

// R25 = R23 restored (session optimum, 237.4 us device-verified):
// 8 waves x 2 tiles, 1 bar/step, chunk-burst reg-resident ax, CHAINED MFMA
// pair (R24 proved independent+adds is 35cy/step worse), packed-pair act,
// emb writes spread j=1..5, prefetch at j=6, vmcnt-floating x loads.
// Ledger of falsified alternatives: 16/4-wave mappings (+220/+175 cy),
// 2 bars/step (+450), per-step ax (+180), de-phased dual blocks (net loss),
// independent MFMA pair (+35). This is the structural floor: ~1112 cy/step =
// issue(~540) + exposed chain(~400) + barrier(~170), serialized 512x.
__global__ __launch_bounds__(512, 2) void lstm_mfma16_kernel(
    const float* __restrict__ x,     const float* __restrict__ Wemb,
    const float* __restrict__ Wih1,  const float* __restrict__ Whh1,
    const float* __restrict__ b1,    const float* __restrict__ Wih2,
    const float* __restrict__ b2,    const float* __restrict__ Wout,
    const float* __restrict__ bout,  float* __restrict__ out)
{
    __shared__ __align__(16) _Float16 P[2][2][4][16][8];       // 4096 B  h-panel dbuf
    __shared__ __align__(16) _Float16 Pe[2][CHUNK][4][16][8];  // 16384 B emb panel dbuf
    __shared__ __align__(16) float h2tmp[16 * 64];             // 4096 B
    __shared__ __align__(16) float h2s[256 * 16];              // 16384 B
    __shared__ float part[32 * 16 * 2];                        // 4096 B

    const int t   = threadIdx.x;
    const int l   = t & 63;
    const int w   = t >> 6;      // wave 0..7; owns tiles 2w, 2w+1
    const int m   = l & 15;      // A-row / B col (batch) / D col
    const int q   = l >> 4;      // quad
    const int b0  = blockIdx.x * 16;

    // ---- weight fragments for both tiles (exp2-domain scaled) --------------
    f16x8 whh[2][2], whE[2];
    f32x4 bias4[2];
    #pragma unroll
    for (int tt = 0; tt < 2; ++tt) {
        const int tau = 2 * w + tt;
        const int g = m & 3;
        const float sc = (g == 2) ? TWOLOG2E : -LOG2E;
        const int n = g * 64 + 4 * tau + (m >> 2);
        #pragma unroll
        for (int c = 0; c < 2; ++c)
            #pragma unroll
            for (int jj = 0; jj < 8; ++jj)
                whh[tt][c][jj] = (_Float16)(Whh1[n * 64 + c * 32 + (q << 3) + jj] * sc);
        #pragma unroll
        for (int jj = 0; jj < 8; ++jj) {
            int k = (q << 3) + jj;
            whE[tt][jj] = (_Float16)((k < 20) ? Wih1[n * 20 + k] * sc : 0.0f);
        }
        #pragma unroll
        for (int r = 0; r < 4; ++r) {
            float scr = (r == 2) ? TWOLOG2E : -LOG2E;
            bias4[tt][r] = b1[r * 64 + 4 * tau + q] * scr;
        }
    }

    // lane's act cells: units 8w+q (tile A), 8w+4+q (tile B), batch m
    const int myuA = 8 * w + q;
    const int myuB = 8 * w + 4 + q;
    _Float16* hwA = &P[0][myuA >> 5][(myuA >> 3) & 3][m][myuA & 7];
    _Float16* hwB = &P[0][myuB >> 5][(myuB >> 3) & 3][m][myuB & 7];
    const _Float16* rb = &P[0][0][q][m][0];   // B-fragment base (lane-linear)
    // parity stride = one P buffer = 1024 f16; Pe buffer stride = 4096 f16

    // ---- emb writer slots: v = t + 512k, k=0..4 (2560 = 5*512, all valid) --
    // pair = v/20 -> (batch = pair&15, s = pair>>4), dim d = v%20
    const float* xp[5]; _Float16* pe[5];
    float we0[5], we1[5];
    float2 xv[5];
    #pragma unroll
    for (int k = 0; k < 5; ++k) {
        int v  = t + 512 * k;
        int d  = v % 20, pr = v / 20;
        int bb = pr & 15, s = pr >> 4;
        we0[k] = Wemb[2 * d];
        we1[k] = Wemb[2 * d + 1];
        pe[k]  = &Pe[0][s][d >> 3][bb][d & 7];
        xp[k]  = x + (size_t)(b0 + bb) * (2 * NSTEP) + 2 * s;
        xv[k]  = *(const float2*)xp[k];                    // chunk-0 data
    }

    // ---- zero P[0] (h(-1)=0) and all of Pe (pads d=20..31 stay 0 forever) --
    ((_Float16*)P)[t]       = (_Float16)0.0f;
    ((_Float16*)P)[t + 512] = (_Float16)0.0f;
    {
        _Float16* pz = (_Float16*)Pe;
        #pragma unroll
        for (int k = 0; k < 16; ++k) pz[t + 512 * k] = (_Float16)0.0f;
    }
    __syncthreads();
    // fill Pe[0] with chunk 0's panel, then prefetch chunk 1's x
    #pragma unroll
    for (int k = 0; k < 5; ++k)
        pe[k][0] = (_Float16)fmaxf(fmaf(xv[k].x, we0[k], xv[k].y * we1[k]), 0.0f);
    #pragma unroll
    for (int k = 0; k < 5; ++k) { xp[k] += 2 * CHUNK; xv[k] = *(const float2*)xp[k]; }
    __syncthreads();

    // ---- main recurrence: 64 chunks x 8 steps ------------------------------
    f32x2 cst = {0.0f, 0.0f};
    for (int ch = 0; ch < NCHUNK; ++ch) {
        const int pb = ch & 1;                           // Pe read buffer
        const _Float16* peR = (const _Float16*)Pe + pb * 4096;

        // phase B: ax[tile][j] = Wih*e(t) + b, in registers (lane == consumer)
        f32x4 axA[CHUNK], axB[CHUNK];
        #pragma unroll
        for (int j = 0; j < CHUNK; ++j) {
            f16x8 fe = *(const f16x8*)(peR + j * 512 + q * 128 + m * 8);
            axA[j] = __builtin_amdgcn_mfma_f32_16x16x32_f16(whE[0], fe, bias4[0], 0, 0, 0);
            axB[j] = __builtin_amdgcn_mfma_f32_16x16x32_f16(whE[1], fe, bias4[1], 0, 0, 0);
        }

        // phase C: 8 recurrence steps, parity static per unrolled slot
        #pragma unroll
        for (int j = 0; j < CHUNK; ++j) {
            const int pr = j & 1;
            f16x8 f0 = *(const f16x8*)(rb + pr * 1024);
            f16x8 f1 = *(const f16x8*)(rb + pr * 1024 + 512);
            f32x4 aA = __builtin_amdgcn_mfma_f32_16x16x32_f16(whh[0][0], f0, axA[j], 0, 0, 0);
            f32x4 aB = __builtin_amdgcn_mfma_f32_16x16x32_f16(whh[1][0], f0, axB[j], 0, 0, 0);
            aA = __builtin_amdgcn_mfma_f32_16x16x32_f16(whh[0][1], f1, aA, 0, 0, 0);
            aB = __builtin_amdgcn_mfma_f32_16x16x32_f16(whh[1][1], f1, aB, 0, 0, 0);
            f32x2 gi = {aA[0], aB[0]}, gf = {aA[1], aB[1]};
            f32x2 gg = {aA[2], aB[2]}, go = {aA[3], aB[3]};
            f32x2 hv = lstm_act2_(gi, gf, gg, go, cst);
            hwA[(pr ^ 1) * 1024] = (_Float16)hv[0];
            hwB[(pr ^ 1) * 1024] = (_Float16)hv[1];
            // emb writes for chunk ch+1 spread one per step (j=1..5);
            // x prefetch for chunk ch+2 at j=6. Pe[pb^1]'s first reader is
            // next chunk's phase B (after this chunk's last barrier);
            // last chunk writes stale data to a dead buffer.
            if (j >= 1 && j <= 5) {
                const int k = j - 1;
                pe[k][(pb ^ 1) * 4096] =
                    (_Float16)fmaxf(fmaf(xv[k].x, we0[k], xv[k].y * we1[k]), 0.0f);
            }
            if (j == 6 && ch + 2 < NCHUNK) {
                #pragma unroll
                for (int k = 0; k < 5; ++k) { xp[k] += 2 * CHUNK; xv[k] = *(const float2*)xp[k]; }
            }
            bar_();
        }
    }
    // final h(511) in P[0]

    // ---- epilogue: h64 to fp32 (1024 values, two per thread) ---------------
    #pragma unroll
    for (int r = 0; r < 2; ++r) {
        int tt = t + 512 * r;
        int b = tt >> 6, k = tt & 63;
        h2tmp[tt] = (float)P[0][k >> 5][(k >> 3) & 3][b][k & 7];
    }
    __syncthreads();

    // ---- LSTM2 (single step, h=c=0 -> f-gate irrelevant) -------------------
    {
        const int u = t & 255;
        const int bh0 = (t >> 8) * 8;               // 2 groups x 8 batches
        float acci[8], accg[8], acco[8];
        float bi2 = b2[u], bg2 = b2[512 + u], bo2 = b2[768 + u];
        #pragma unroll
        for (int b = 0; b < 8; ++b) { acci[b] = bi2; accg[b] = bg2; acco[b] = bo2; }
        for (int k4 = 0; k4 < 64; k4 += 4) {
            float4 wi = *(const float4*)&Wih2[(size_t)u * 64 + k4];
            float4 wg = *(const float4*)&Wih2[(size_t)(512 + u) * 64 + k4];
            float4 wo = *(const float4*)&Wih2[(size_t)(768 + u) * 64 + k4];
            #pragma unroll
            for (int b = 0; b < 8; ++b) {
                float4 hb = *(const float4*)&h2tmp[(bh0 + b) * 64 + k4];
                acci[b] += wi.x * hb.x + wi.y * hb.y + wi.z * hb.z + wi.w * hb.w;
                accg[b] += wg.x * hb.x + wg.y * hb.y + wg.z * hb.z + wg.w * hb.w;
                acco[b] += wo.x * hb.x + wo.y * hb.y + wo.z * hb.z + wo.w * hb.w;
            }
        }
        #pragma unroll
        for (int b = 0; b < 8; ++b) {
            float c2 = sig_(acci[b]) * tanh_(accg[b]);
            h2s[u * 16 + bh0 + b] = sig_(acco[b]) * tanh_(c2);
        }
    }
    __syncthreads();

    // ---- output projection --------------------------------------------------
    {
        int b = t & 15, grp = t >> 4;            // 32 groups x 8 units
        float p0 = 0.f, p1 = 0.f;
        #pragma unroll
        for (int uu = grp * 8; uu < grp * 8 + 8; ++uu) {
            float hvv = h2s[uu * 16 + b];
            p0 += hvv * Wout[uu];
            p1 += hvv * Wout[256 + uu];
        }
        part[(grp * 16 + b) * 2 + 0] = p0;
        part[(grp * 16 + b) * 2 + 1] = p1;
    }
    __syncthreads();
    if (t < 32) {
        int b = t >> 1, o = t & 1;
        float s0 = bout[o];
        for (int grp = 0; grp < 32; ++grp) s0 += part[(grp * 16 + b) * 2 + o];
        out[(size_t)(b0 + b) * 2 + o] = s0;
    }
}

extern "C" void kernel_launch(void* const* d_in, const int* in_sizes, int n_in,
                              void* d_out, int out_size, void* d_ws, size_t ws_size,
                              hipStream_t stream) {
    const float* x    = (const float*)d_in[0];
    const float* Wemb = (const float*)d_in[1];
    const float* Wih1 = (const float*)d_in[2];
    const float* Whh1 = (const float*)d_in[3];
    const float* b1   = (const float*)d_in[4];
    const float* Wih2 = (const float*)d_in[5];
    // d_in[6] = Whh2: unused (h=c=0 at LSTM2's single step)
    const float* b2   = (const float*)d_in[7];
    const float* Wout = (const float*)d_in[8];
    const float* bout = (const float*)d_in[9];
    float* out = (float*)d_out;

    lstm_mfma16_kernel<<<256, 512, 0, stream>>>(
        x, Wemb, Wih1, Whh1, b1, Wih2, b2, Wout, bout, out);
}